// Round 20
// baseline (160.097 us; speedup 1.0000x reference)
//
#include <hip/hip_runtime.h>
#include <cstdint>

typedef __bf16 bf16x8 __attribute__((ext_vector_type(8)));
typedef float f32x16 __attribute__((ext_vector_type(16)));
typedef unsigned int u32;

#define MFMA32(a, b, c) __builtin_amdgcn_mfma_f32_32x32x16_bf16(a, b, c, 0, 0, 0)

static constexpr int NBH = 64;     // B*H
static constexpr int NN  = 4096;
static constexpr int DD  = 64;
static constexpr int MM  = 256;
static constexpr float DATA_NORM = 0.35355339059327373f; // 64^-0.25
static constexpr float RATIO     = 0.0625f;              // 1/sqrt(256)
static constexpr float EPSK      = 1e-4f;

__device__ __forceinline__ unsigned short bfu(float f) {
  return __builtin_bit_cast(unsigned short, (__bf16)f);
}
__device__ __forceinline__ unsigned pk2(float a, float b) {
  return (unsigned)bfu(a) | ((unsigned)bfu(b) << 16);
}
// VT layout: [ncb:4][wrap(e):8][grp(e):8 x 16B], grp = (e&7)^(wrap&7); +2*(n&7) for element
__device__ __forceinline__ int vtByte(int ncb, int e) {
  const int wrap = e >> 3;
  const int grp = (e & 7) ^ (wrap & 7);
  return ncb * 1024 + wrap * 128 + grp * 16;
}
// async global->LDS, 4B per lane (lds dest wave-uniform base + lane*4)
__device__ __forceinline__ void gload_lds4(const float* g, void* lds) {
  __builtin_amdgcn_global_load_lds((const __attribute__((address_space(1))) u32*)g,
                                   (__attribute__((address_space(3))) u32*)lds, 4, 0, 0);
}

// ---------------- prep: frag-packed proj (layout serves as both A-frag and B-frag) ----------------
__global__ void prep_proj(const float* __restrict__ proj, unsigned short* __restrict__ paU) {
  const int l = threadIdx.x, combo = blockIdx.x; // 32 blocks x 64 thr
  const int mt = combo >> 2, kt = combo & 3;
  const int m = mt * 32 + (l & 31);
  const int d0 = kt * 16 + 8 * (l >> 5);
  unsigned short pk[8];
#pragma unroll
  for (int j = 0; j < 8; ++j) pk[j] = bfu(DATA_NORM * proj[m * 64 + d0 + j]);
  uint4 u = make_uint4(pk[0] | ((unsigned)pk[1] << 16), pk[2] | ((unsigned)pk[3] << 16),
                       pk[4] | ((unsigned)pk[5] << 16), pk[6] | ((unsigned)pk[7] << 16));
  *(uint4*)(paU + (size_t)(combo * 64 + l) * 8) = u;
}

// ---------------- k_pass v14 (r18 version restored — 92 us, no spill) ----------------------------
__global__ __launch_bounds__(256, 3) void k_pass(
    const float* __restrict__ kk, const float* __restrict__ vv,
    const bf16x8* __restrict__ paG, float* __restrict__ s1p,
    float* __restrict__ s2p, unsigned* __restrict__ kmaxp, int NC) {
  // LDS: K dbuf 2 x (32 rows x 264B) = 16896; V dbuf 2 x 4096 = 8192
  __shared__ __align__(16) char smc[16896 + 8192];
  char* kbuf0 = smc;
  char* kbuf1 = smc + 8448;
  char* vbufB = smc + 16896;

  const int t = threadIdx.x, l = t & 63, wv = t >> 6;   // wv 0..3
  const int l31 = l & 31, lh = l >> 5;
  // twins (ms=0/1) are 8 blockIdx apart -> same XCD under round-robin dispatch
  const int u = blockIdx.x;
  const int lin = (u >> 4) * 8 + (u & 7);
  const int ms = (u >> 3) & 1;
  const int bh = lin / NC, nc = lin - bh * NC;
  const int rowsPB = NN / NC, ntiles = rowsPB >> 5;
  const float* kb = kk + (size_t)bh * NN * DD;
  const float* vb = vv + (size_t)bh * NN * DD;
  const int base0 = nc * rowsPB;
  const int mslice = ms * 4 + wv;                        // m = mslice*32 + l31
  const bool doS2 = (ms == 0);
  const int ns = t >> 3, se0 = (t & 7) * 8;              // V stager: row ns, 8 e-cols

  bf16x8 pb[4];  // proj B-frags for this m-slice
#pragma unroll
  for (int kt = 0; kt < 4; ++kt) pb[kt] = paG[(mslice * 4 + kt) * 64 + l];

  f32x16 accS[2];
#pragma unroll
  for (int et = 0; et < 2; ++et)
#pragma unroll
    for (int i = 0; i < 16; ++i) accS[et][i] = 0.f;
  float s2loc[8] = {0.f, 0.f, 0.f, 0.f, 0.f, 0.f, 0.f, 0.f};
  float gmax = -3.0e38f;

  float v8[8];
  bf16x8 KH[4];
  float nrm = 0.f;

  // prologue: K(0) async -> kbuf0; V(0) -> regs
#pragma unroll
  for (int i = 0; i < 8; ++i) {
    const int r = wv * 8 + i;
    gload_lds4(kb + (size_t)(base0 + r) * DD + l, kbuf0 + r * 264);
  }
  {
    const float* s = vb + (size_t)(base0 + ns) * DD + se0;
    *(float4*)&v8[0] = *(const float4*)s;
    *(float4*)&v8[4] = *(const float4*)(s + 4);
  }
  __syncthreads();  // drains K(0)
  // pack K(0) + norm
  {
    float ds = 0.f;
#pragma unroll
    for (int kt = 0; kt < 4; ++kt) {
      const char* p = kbuf0 + l31 * 264 + kt * 64 + lh * 32;
      float2 a = *(const float2*)(p);
      float2 b = *(const float2*)(p + 8);
      float2 c = *(const float2*)(p + 16);
      float2 d = *(const float2*)(p + 24);
      ds += a.x * a.x + a.y * a.y + b.x * b.x + b.y * b.y +
            c.x * c.x + c.y * c.y + d.x * d.x + d.y * d.y;
      KH[kt] = __builtin_bit_cast(bf16x8, make_uint4(pk2(a.x, a.y), pk2(b.x, b.y),
                                                     pk2(c.x, c.y), pk2(d.x, d.y)));
    }
    ds += __shfl_xor(ds, 32);
    nrm = ds * 0.0625f;    // diag of K row l31
  }
  // stage V(0) raw bf16
  {
    const int ncb = ns >> 3, np2 = (ns & 7) * 2;
#pragma unroll
    for (int j = 0; j < 8; ++j) {
      s2loc[j] += v8[j];
      *(unsigned short*)(vbufB + vtByte(ncb, se0 + j) + np2) = bfu(v8[j]);
    }
  }
  if (ntiles > 1) {
    // issue K(1); load V(1)
#pragma unroll
    for (int i = 0; i < 8; ++i) {
      const int r = wv * 8 + i;
      gload_lds4(kb + (size_t)(base0 + 32 + r) * DD + l, kbuf1 + r * 264);
    }
    const float* s = vb + (size_t)(base0 + 32 + ns) * DD + se0;
    *(float4*)&v8[0] = *(const float4*)s;
    *(float4*)&v8[4] = *(const float4*)(s + 4);
  }
  __syncthreads();  // V(0) visible; K(1)/V(1) drained (one-time cost)

  for (int tile = 0; tile < ntiles; ++tile) {
    // C: stage V(t+1) from v8 regs (frees v8 for the prefetch below)
    if (tile + 1 < ntiles) {
      char* vtn = vbufB + ((tile + 1) & 1) * 4096;
      const int ncb = ns >> 3, np2 = (ns & 7) * 2;
#pragma unroll
      for (int j = 0; j < 8; ++j) {
        s2loc[j] += v8[j];
        *(unsigned short*)(vtn + vtByte(ncb, se0 + j) + np2) = bfu(v8[j]);
      }
    }
    // D: issue K(t+2) + V(t+2) NOW — full A/B/F phase in flight before the barrier drain.
    if (tile + 2 < ntiles) {
      char* kdst = (tile & 1) ? kbuf1 : kbuf0;
      const int nb = base0 + (tile + 2) * 32;
#pragma unroll
      for (int i = 0; i < 8; ++i) {
        const int r = wv * 8 + i;
        gload_lds4(kb + (size_t)(nb + r) * DD + l, kdst + r * 264);
      }
      const float* s = vb + (size_t)(nb + ns) * DD + se0;
      *(float4*)&v8[0] = *(const float4*)s;
      *(float4*)&v8[4] = *(const float4*)(s + 4);
    }
    // A: phase A (4 MFMA, single bf16 K)
    f32x16 acc;
#pragma unroll
    for (int i = 0; i < 16; ++i) acc[i] = 0.f;
#pragma unroll
    for (int kt = 0; kt < 4; ++kt) acc = MFMA32(KH[kt], pb[kt], acc);
#pragma unroll
    for (int i = 0; i < 16; ++i) gmax = fmaxf(gmax, acc[i]);
    // B: E = exp(xd - diag); half-swap; PV from V LDS
    {
      const char* vtc = vbufB + (tile & 1) * 4096;
#pragma unroll
      for (int kc = 0; kc < 2; ++kc) {
        float eA[4], eB[4];
#pragma unroll
        for (int c = 0; c < 4; ++c) {
          const float dgA = __shfl(nrm, kc * 16 + 4 * lh + c);
          const float dgB = __shfl(nrm, kc * 16 + 4 * lh + 8 + c);
          eA[c] = __expf(acc[kc * 8 + c] - dgA);
          eB[c] = __expf(acc[kc * 8 + 4 + c] - dgB);
        }
        unsigned p00 = pk2(eA[0], eA[1]), p01 = pk2(eA[2], eA[3]);
        unsigned p10 = pk2(eB[0], eB[1]), p11 = pk2(eB[2], eB[3]);
        unsigned o00 = __shfl_xor(p00, 32), o01 = __shfl_xor(p01, 32);
        unsigned o10 = __shfl_xor(p10, 32), o11 = __shfl_xor(p11, 32);
        uint4 W;
        W.x = lh ? o10 : p00;
        W.y = lh ? o11 : p01;
        W.z = lh ? p10 : o00;
        W.w = lh ? p11 : o01;
        bf16x8 af = __builtin_bit_cast(bf16x8, W);
#pragma unroll
        for (int et = 0; et < 2; ++et) {
          const int e = et * 32 + l31;
          bf16x8 bv = *(const bf16x8*)(vtc + vtByte(kc * 2 + lh, e));
          accS[et] = MFMA32(af, bv, accS[et]);
        }
      }
    }
    // F: pack K(t+1) from kbuf[(t+1)&1] (drained at previous barrier)
    if (tile + 1 < ntiles) {
      const char* ksrc = ((tile + 1) & 1) ? kbuf1 : kbuf0;
      float ds = 0.f;
#pragma unroll
      for (int kt = 0; kt < 4; ++kt) {
        const char* p = ksrc + l31 * 264 + kt * 64 + lh * 32;
        float2 a = *(const float2*)(p);
        float2 b = *(const float2*)(p + 8);
        float2 c = *(const float2*)(p + 16);
        float2 d = *(const float2*)(p + 24);
        ds += a.x * a.x + a.y * a.y + b.x * b.x + b.y * b.y +
              c.x * c.x + c.y * c.y + d.x * d.x + d.y * d.y;
        KH[kt] = __builtin_bit_cast(bf16x8, make_uint4(pk2(a.x, a.y), pk2(b.x, b.y),
                                                       pk2(c.x, c.y), pk2(d.x, d.y)));
      }
      ds += __shfl_xor(ds, 32);
      nrm = ds * 0.0625f;
    }
    // barrier: V(t+1) visible; K(t+2)/V(t+2) drained (issued a full phase ago)
    __syncthreads();
  }
  // ---- S1 partials (shared slab per (bh,nc); twins cover disjoint m) ----
  {
    float* o = s1p + (size_t)(bh * NC + nc) * (MM * 64);
#pragma unroll
    for (int et = 0; et < 2; ++et)
#pragma unroll
      for (int i = 0; i < 16; ++i) {
        const int m = mslice * 32 + 4 * lh + (i & 3) + 8 * (i >> 2);
        o[m * 64 + et * 32 + l31] = accS[et][i];
      }
  }
  // ---- S2 reduce via LDS scratch (reuse smc) ----
  {
    float* scr = (float*)smc;  // [256][8]
#pragma unroll
    for (int j = 0; j < 8; ++j) scr[t * 8 + j] = s2loc[j];
    __syncthreads();
    if (doS2 && t < 64) {
      float s = 0.f;
      for (int k2 = 0; k2 < 32; ++k2) s += scr[((k2 << 3) | (t >> 3)) * 8 + (t & 7)];
      s2p[(size_t)(bh * NC + nc) * 64 + t] = s;
    }
  }
  // ---- global max: per-wave reduce + atomic ----
#pragma unroll
  for (int off = 32; off; off >>= 1) gmax = fmaxf(gmax, __shfl_xor(gmax, off));
  if (l == 0) {
    unsigned b = __float_as_uint(gmax);
    unsigned key = (b & 0x80000000u) ? ~b : (b | 0x80000000u);
    atomicMax(kmaxp, key);
  }
}

// ---------------- ctx_finalize v2 (16-way per bh — 1024 blocks, 4/CU) ----------------------------
__global__ void ctx_finalize(const float* __restrict__ s1p, const float* __restrict__ s2p,
                             const unsigned* __restrict__ kmaxp, unsigned short* __restrict__ cbU,
                             float* __restrict__ epstP, int NC) {
  __shared__ float ctxl[16 * 64];
  __shared__ float s2s[64];
  __shared__ float csr[4 * 64];
  const int t = threadIdx.x;
  const int bh = blockIdx.x >> 4, gg = blockIdx.x & 15;   // gg = 16-row slice = kt index
  const unsigned key = *kmaxp;
  const unsigned b = (key & 0x80000000u) ? (key & 0x7fffffffu) : ~key;
  const float stab = __uint_as_float(b);
  const float esc = RATIO * __expf(-stab);
  if (t < 64) {
    float s = 0.f;
    for (int nc = 0; nc < NC; ++nc) s += s2p[(size_t)(bh * NC + nc) * 64 + t];
    s2s[t] = RATIO * EPSK * s;
  }
  __syncthreads();
  const int e = t & 63, w = t >> 6;
  float cs = 0.f;
#pragma unroll
  for (int i = 0; i < 4; ++i) {
    const int ml = i * 4 + w;                     // local m within this 16-row slice
    const int idx = (gg * 16 + ml) * 64 + e;      // global (m, e)
    float s = 0.f;
#pragma unroll
    for (int nc = 0; nc < 8; ++nc) s += s1p[(size_t)(bh * NC + nc) * 16384 + idx];
    const float val = esc * s + s2s[e];
    ctxl[ml * 64 + e] = val;
    cs += val;
  }
  csr[w * 64 + e] = cs;
  __syncthreads();
  if (t < 64)
    epstP[(size_t)(bh * 16 + gg) * 64 + t] =
        RATIO * EPSK * (csr[t] + csr[64 + t] + csr[128 + t] + csr[192 + t]);
  // pack cb B-frags for this slice: kt = gg, et = 0/1 (threads 0..127)
  if (t < 128) {
    const int et = t >> 6, l = t & 63;
    unsigned short pk[8];
#pragma unroll
    for (int j = 0; j < 8; ++j) {
      const int ml = 8 * (l >> 5) + j;
      const int e2 = et * 32 + (l & 31);
      pk[j] = bfu(ctxl[ml * 64 + e2]);
    }
    uint4 u = make_uint4(pk[0] | ((unsigned)pk[1] << 16), pk[2] | ((unsigned)pk[3] << 16),
                         pk[4] | ((unsigned)pk[5] << 16), pk[6] | ((unsigned)pk[7] << 16));
    *(uint4*)(cbU + (size_t)bh * 16384 + (size_t)((gg * 2 + et) * 64 + l) * 8) = u;
  }
}

// ---------------- q_pass v11: persistent over 2 row-chunks (grid 1024) — prologue (ept/pa/cb base)
//                  amortized; per-chunk body identical to v10. ------------------------------------
__global__ __launch_bounds__(256, 3) void q_pass(
    const float* __restrict__ qq, const bf16x8* __restrict__ paG,
    const bf16x8* __restrict__ cbG, const float* __restrict__ epstP,
    float* __restrict__ outp) {
  const int t = threadIdx.x, l = t & 63, wv = t >> 6;
  const int l31 = l & 31, lh = l >> 5;
  const int bid = blockIdx.x, bh = bid >> 4, nc = bid & 15;  // 16 chunks of 256 rows
  const float* qb = qq + (size_t)bh * NN * DD;
  float* ob = outp + (size_t)bh * NN * DD;
  const bf16x8* cbB = cbG + (size_t)bh * 2048;

  float ept0 = 0.f, ept1 = 0.f;
#pragma unroll
  for (int g = 0; g < 16; ++g) {
    ept0 += epstP[(size_t)(bh * 16 + g) * 64 + l31];
    ept1 += epstP[(size_t)(bh * 16 + g) * 64 + 32 + l31];
  }

  for (int half = 0; half < 2; ++half) {
    const int base = nc * 256 + half * 128 + wv * 32;

    bf16x8 QH[4];
    float ds = 0.f;
#pragma unroll
    for (int kt = 0; kt < 4; ++kt) {
      const float* p = qb + (size_t)(base + l31) * DD + kt * 16 + 8 * lh;
      float x[8];
      *(float4*)&x[0] = *(const float4*)p;
      *(float4*)&x[4] = *(const float4*)(p + 4);
#pragma unroll
      for (int j = 0; j < 8; ++j) ds += x[j] * x[j];
      QH[kt] = __builtin_bit_cast(bf16x8, make_uint4(pk2(x[0], x[1]), pk2(x[2], x[3]),
                                                     pk2(x[4], x[5]), pk2(x[6], x[7])));
    }
    ds += __shfl_xor(ds, 32);
    const float diag = ds * 0.0625f;

    f32x16 out0, out1;
#pragma unroll
    for (int i = 0; i < 16; ++i) { out0[i] = 0.f; out1[i] = 0.f; }
    float lmax = -3.0e38f;

    bf16x8 pa[4], cbv[4];
#pragma unroll
    for (int kt = 0; kt < 4; ++kt) pa[kt] = paG[kt * 64 + l];
#pragma unroll
    for (int j = 0; j < 4; ++j) cbv[j] = cbB[j * 64 + l];

    for (int mt = 0; mt < 8; ++mt) {
      // phase A: 4 MFMA (single bf16 Q)
      f32x16 acc;
#pragma unroll
      for (int i = 0; i < 16; ++i) acc[i] = 0.f;
#pragma unroll
      for (int kt = 0; kt < 4; ++kt) acc = MFMA32(pa[kt], QH[kt], acc);
      // prefetch pa and cb for mt+1 (consumed a full mt-iteration later)
      bf16x8 pan[4], cbn[4];
      if (mt < 7) {
#pragma unroll
        for (int kt = 0; kt < 4; ++kt) pan[kt] = paG[((mt + 1) * 4 + kt) * 64 + l];
#pragma unroll
        for (int j = 0; j < 4; ++j) cbn[j] = cbB[((mt + 1) * 4 + j) * 64 + l];
      }
#pragma unroll
      for (int i = 0; i < 16; ++i) lmax = fmaxf(lmax, acc[i]);
#pragma unroll
      for (int kc = 0; kc < 2; ++kc) {
        float eA[4], eB[4];
#pragma unroll
        for (int c = 0; c < 4; ++c) {
          eA[c] = __expf(acc[kc * 8 + c] - diag);
          eB[c] = __expf(acc[kc * 8 + 4 + c] - diag);
        }
        unsigned p00 = pk2(eA[0], eA[1]), p01 = pk2(eA[2], eA[3]);
        unsigned p10 = pk2(eB[0], eB[1]), p11 = pk2(eB[2], eB[3]);
        unsigned o00 = __shfl_xor(p00, 32), o01 = __shfl_xor(p01, 32);
        unsigned o10 = __shfl_xor(p10, 32), o11 = __shfl_xor(p11, 32);
        uint4 W;
        W.x = lh ? o10 : p00;
        W.y = lh ? o11 : p01;
        W.z = lh ? p10 : o00;
        W.w = lh ? p11 : o01;
        bf16x8 af = __builtin_bit_cast(bf16x8, W);
        out0 = MFMA32(af, cbv[kc * 2 + 0], out0);
        out1 = MFMA32(af, cbv[kc * 2 + 1], out1);
      }
      if (mt < 7) {
#pragma unroll
        for (int kt = 0; kt < 4; ++kt) pa[kt] = pan[kt];
#pragma unroll
        for (int j = 0; j < 4; ++j) cbv[j] = cbn[j];
      }
    }
    const float rmaxp = fmaxf(lmax, __shfl_xor(lmax, 32));
#pragma unroll
    for (int i = 0; i < 16; ++i) {
      const int rr = 4 * lh + (i & 3) + 8 * (i >> 2);
      const float st = __shfl(rmaxp, rr);
      const float sc = RATIO * __expf(-st);
      const int row = base + rr;
      ob[(size_t)row * 64 + l31]      = sc * out0[i] + ept0;
      ob[(size_t)row * 64 + 32 + l31] = sc * out1[i] + ept1;
    }
  }
}

extern "C" void kernel_launch(void* const* d_in, const int* in_sizes, int n_in,
                              void* d_out, int out_size, void* d_ws, size_t ws_size,
                              hipStream_t stream) {
  (void)in_sizes; (void)n_in; (void)out_size;
  const float* q    = (const float*)d_in[0];
  const float* k    = (const float*)d_in[1];
  const float* v    = (const float*)d_in[2];
  const float* proj = (const float*)d_in[3];
  float* out = (float*)d_out;
  char* wsb = (char*)d_ws;

  int NC = 8;
  auto need = [&](int nc) -> size_t {
    size_t off = 256 + 32768;                  // key + pa
    off += (size_t)nc * NBH * MM * 64 * 4;     // S1 partials
    off += (size_t)nc * NBH * 64 * 4;          // S2 partials
    off += (size_t)NBH * MM * 64 * 2;          // cb (bf16)
    off += (size_t)NBH * 16 * 64 * 4;          // epst partials (16-way)
    return off;
  };
  while (NC > 1 && need(NC) > ws_size) NC >>= 1;

  unsigned* kmaxp = (unsigned*)wsb;
  bf16x8* paG = (bf16x8*)(wsb + 256);
  float* s1p = (float*)(wsb + 256 + 32768);
  float* s2p = (float*)((char*)s1p + (size_t)NC * NBH * MM * 64 * 4);
  unsigned short* cbU = (unsigned short*)((char*)s2p + (size_t)NC * NBH * 64 * 4);
  float* epstP = (float*)((char*)cbU + (size_t)NBH * MM * 64 * 2);

  hipMemsetAsync(wsb, 0, 4, stream); // kmax key = 0 (== -inf under monotone map)
  hipLaunchKernelGGL(prep_proj, dim3(32), dim3(64), 0, stream, proj, (unsigned short*)paG);
  hipLaunchKernelGGL(k_pass, dim3(NBH * NC * 2), dim3(256), 0, stream, k, v, paG, s1p, s2p, kmaxp, NC);
  hipLaunchKernelGGL(ctx_finalize, dim3(NBH * 16), dim3(256), 0, stream, s1p, s2p, kmaxp, cbU, epstP, NC);
  hipLaunchKernelGGL(q_pass, dim3(NBH * 16), dim3(256), 0, stream, q, paG, (const bf16x8*)cbU, epstP, out);
}

// Round 21
// 146.943 us; speedup vs baseline: 1.0895x; 1.0895x over previous
//
#include <hip/hip_runtime.h>
#include <cstdint>

typedef __bf16 bf16x8 __attribute__((ext_vector_type(8)));
typedef float f32x16 __attribute__((ext_vector_type(16)));
typedef unsigned int u32;

#define MFMA32(a, b, c) __builtin_amdgcn_mfma_f32_32x32x16_bf16(a, b, c, 0, 0, 0)

static constexpr int NBH = 64;     // B*H
static constexpr int NN  = 4096;
static constexpr int DD  = 64;
static constexpr int MM  = 256;
static constexpr float DATA_NORM = 0.35355339059327373f; // 64^-0.25
static constexpr float RATIO     = 0.0625f;              // 1/sqrt(256)
static constexpr float EPSK      = 1e-4f;

__device__ __forceinline__ unsigned short bfu(float f) {
  return __builtin_bit_cast(unsigned short, (__bf16)f);
}
__device__ __forceinline__ unsigned pk2(float a, float b) {
  return (unsigned)bfu(a) | ((unsigned)bfu(b) << 16);
}
// VT layout: [ncb:4][wrap(e):8][grp(e):8 x 16B], grp = (e&7)^(wrap&7); +2*(n&7) for element
__device__ __forceinline__ int vtByte(int ncb, int e) {
  const int wrap = e >> 3;
  const int grp = (e & 7) ^ (wrap & 7);
  return ncb * 1024 + wrap * 128 + grp * 16;
}
// async global->LDS, 4B per lane (lds dest wave-uniform base + lane*4)
__device__ __forceinline__ void gload_lds4(const float* g, void* lds) {
  __builtin_amdgcn_global_load_lds((const __attribute__((address_space(1))) u32*)g,
                                   (__attribute__((address_space(3))) u32*)lds, 4, 0, 0);
}

// ---------------- prep: frag-packed proj (layout serves as both A-frag and B-frag) ----------------
__global__ void prep_proj(const float* __restrict__ proj, unsigned short* __restrict__ paU) {
  const int l = threadIdx.x, combo = blockIdx.x; // 32 blocks x 64 thr
  const int mt = combo >> 2, kt = combo & 3;
  const int m = mt * 32 + (l & 31);
  const int d0 = kt * 16 + 8 * (l >> 5);
  unsigned short pk[8];
#pragma unroll
  for (int j = 0; j < 8; ++j) pk[j] = bfu(DATA_NORM * proj[m * 64 + d0 + j]);
  uint4 u = make_uint4(pk[0] | ((unsigned)pk[1] << 16), pk[2] | ((unsigned)pk[3] << 16),
                       pk[4] | ((unsigned)pk[5] << 16), pk[6] | ((unsigned)pk[7] << 16));
  *(uint4*)(paU + (size_t)(combo * 64 + l) * 8) = u;
}

// ---------------- k_pass v14 + T5 setprio around the MFMA compute section ------------------------
__global__ __launch_bounds__(256, 3) void k_pass(
    const float* __restrict__ kk, const float* __restrict__ vv,
    const bf16x8* __restrict__ paG, float* __restrict__ s1p,
    float* __restrict__ s2p, unsigned* __restrict__ kmaxp, int NC) {
  // LDS: K dbuf 2 x (32 rows x 264B) = 16896; V dbuf 2 x 4096 = 8192
  __shared__ __align__(16) char smc[16896 + 8192];
  char* kbuf0 = smc;
  char* kbuf1 = smc + 8448;
  char* vbufB = smc + 16896;

  const int t = threadIdx.x, l = t & 63, wv = t >> 6;   // wv 0..3
  const int l31 = l & 31, lh = l >> 5;
  // twins (ms=0/1) are 8 blockIdx apart -> same XCD under round-robin dispatch
  const int u = blockIdx.x;
  const int lin = (u >> 4) * 8 + (u & 7);
  const int ms = (u >> 3) & 1;
  const int bh = lin / NC, nc = lin - bh * NC;
  const int rowsPB = NN / NC, ntiles = rowsPB >> 5;
  const float* kb = kk + (size_t)bh * NN * DD;
  const float* vb = vv + (size_t)bh * NN * DD;
  const int base0 = nc * rowsPB;
  const int mslice = ms * 4 + wv;                        // m = mslice*32 + l31
  const bool doS2 = (ms == 0);
  const int ns = t >> 3, se0 = (t & 7) * 8;              // V stager: row ns, 8 e-cols

  bf16x8 pb[4];  // proj B-frags for this m-slice
#pragma unroll
  for (int kt = 0; kt < 4; ++kt) pb[kt] = paG[(mslice * 4 + kt) * 64 + l];

  f32x16 accS[2];
#pragma unroll
  for (int et = 0; et < 2; ++et)
#pragma unroll
    for (int i = 0; i < 16; ++i) accS[et][i] = 0.f;
  float s2loc[8] = {0.f, 0.f, 0.f, 0.f, 0.f, 0.f, 0.f, 0.f};
  float gmax = -3.0e38f;

  float v8[8];
  bf16x8 KH[4];
  float nrm = 0.f;

  // prologue: K(0) async -> kbuf0; V(0) -> regs
#pragma unroll
  for (int i = 0; i < 8; ++i) {
    const int r = wv * 8 + i;
    gload_lds4(kb + (size_t)(base0 + r) * DD + l, kbuf0 + r * 264);
  }
  {
    const float* s = vb + (size_t)(base0 + ns) * DD + se0;
    *(float4*)&v8[0] = *(const float4*)s;
    *(float4*)&v8[4] = *(const float4*)(s + 4);
  }
  __syncthreads();  // drains K(0)
  // pack K(0) + norm
  {
    float ds = 0.f;
#pragma unroll
    for (int kt = 0; kt < 4; ++kt) {
      const char* p = kbuf0 + l31 * 264 + kt * 64 + lh * 32;
      float2 a = *(const float2*)(p);
      float2 b = *(const float2*)(p + 8);
      float2 c = *(const float2*)(p + 16);
      float2 d = *(const float2*)(p + 24);
      ds += a.x * a.x + a.y * a.y + b.x * b.x + b.y * b.y +
            c.x * c.x + c.y * c.y + d.x * d.x + d.y * d.y;
      KH[kt] = __builtin_bit_cast(bf16x8, make_uint4(pk2(a.x, a.y), pk2(b.x, b.y),
                                                     pk2(c.x, c.y), pk2(d.x, d.y)));
    }
    ds += __shfl_xor(ds, 32);
    nrm = ds * 0.0625f;    // diag of K row l31
  }
  // stage V(0) raw bf16
  {
    const int ncb = ns >> 3, np2 = (ns & 7) * 2;
#pragma unroll
    for (int j = 0; j < 8; ++j) {
      s2loc[j] += v8[j];
      *(unsigned short*)(vbufB + vtByte(ncb, se0 + j) + np2) = bfu(v8[j]);
    }
  }
  if (ntiles > 1) {
    // issue K(1); load V(1)
#pragma unroll
    for (int i = 0; i < 8; ++i) {
      const int r = wv * 8 + i;
      gload_lds4(kb + (size_t)(base0 + 32 + r) * DD + l, kbuf1 + r * 264);
    }
    const float* s = vb + (size_t)(base0 + 32 + ns) * DD + se0;
    *(float4*)&v8[0] = *(const float4*)s;
    *(float4*)&v8[4] = *(const float4*)(s + 4);
  }
  __syncthreads();  // V(0) visible; K(1)/V(1) drained (one-time cost)

  for (int tile = 0; tile < ntiles; ++tile) {
    // C: stage V(t+1) from v8 regs (frees v8 for the prefetch below)
    if (tile + 1 < ntiles) {
      char* vtn = vbufB + ((tile + 1) & 1) * 4096;
      const int ncb = ns >> 3, np2 = (ns & 7) * 2;
#pragma unroll
      for (int j = 0; j < 8; ++j) {
        s2loc[j] += v8[j];
        *(unsigned short*)(vtn + vtByte(ncb, se0 + j) + np2) = bfu(v8[j]);
      }
    }
    // D: issue K(t+2) + V(t+2) NOW — full A/B/F phase in flight before the barrier drain.
    if (tile + 2 < ntiles) {
      char* kdst = (tile & 1) ? kbuf1 : kbuf0;
      const int nb = base0 + (tile + 2) * 32;
#pragma unroll
      for (int i = 0; i < 8; ++i) {
        const int r = wv * 8 + i;
        gload_lds4(kb + (size_t)(nb + r) * DD + l, kdst + r * 264);
      }
      const float* s = vb + (size_t)(nb + ns) * DD + se0;
      *(float4*)&v8[0] = *(const float4*)s;
      *(float4*)&v8[4] = *(const float4*)(s + 4);
    }
    // A: phase A (4 MFMA, single bf16 K) — setprio(1): favor compute waves on the CU scheduler
    __builtin_amdgcn_s_setprio(1);
    f32x16 acc;
#pragma unroll
    for (int i = 0; i < 16; ++i) acc[i] = 0.f;
#pragma unroll
    for (int kt = 0; kt < 4; ++kt) acc = MFMA32(KH[kt], pb[kt], acc);
    __builtin_amdgcn_s_setprio(0);
#pragma unroll
    for (int i = 0; i < 16; ++i) gmax = fmaxf(gmax, acc[i]);
    // B: E = exp(xd - diag); half-swap; PV from V LDS
    {
      const char* vtc = vbufB + (tile & 1) * 4096;
#pragma unroll
      for (int kc = 0; kc < 2; ++kc) {
        float eA[4], eB[4];
#pragma unroll
        for (int c = 0; c < 4; ++c) {
          const float dgA = __shfl(nrm, kc * 16 + 4 * lh + c);
          const float dgB = __shfl(nrm, kc * 16 + 4 * lh + 8 + c);
          eA[c] = __expf(acc[kc * 8 + c] - dgA);
          eB[c] = __expf(acc[kc * 8 + 4 + c] - dgB);
        }
        unsigned p00 = pk2(eA[0], eA[1]), p01 = pk2(eA[2], eA[3]);
        unsigned p10 = pk2(eB[0], eB[1]), p11 = pk2(eB[2], eB[3]);
        unsigned o00 = __shfl_xor(p00, 32), o01 = __shfl_xor(p01, 32);
        unsigned o10 = __shfl_xor(p10, 32), o11 = __shfl_xor(p11, 32);
        uint4 W;
        W.x = lh ? o10 : p00;
        W.y = lh ? o11 : p01;
        W.z = lh ? p10 : o00;
        W.w = lh ? p11 : o01;
        bf16x8 af = __builtin_bit_cast(bf16x8, W);
        __builtin_amdgcn_s_setprio(1);
#pragma unroll
        for (int et = 0; et < 2; ++et) {
          const int e = et * 32 + l31;
          bf16x8 bv = *(const bf16x8*)(vtc + vtByte(kc * 2 + lh, e));
          accS[et] = MFMA32(af, bv, accS[et]);
        }
        __builtin_amdgcn_s_setprio(0);
      }
    }
    // F: pack K(t+1) from kbuf[(t+1)&1] (drained at previous barrier)
    if (tile + 1 < ntiles) {
      const char* ksrc = ((tile + 1) & 1) ? kbuf1 : kbuf0;
      float ds = 0.f;
#pragma unroll
      for (int kt = 0; kt < 4; ++kt) {
        const char* p = ksrc + l31 * 264 + kt * 64 + lh * 32;
        float2 a = *(const float2*)(p);
        float2 b = *(const float2*)(p + 8);
        float2 c = *(const float2*)(p + 16);
        float2 d = *(const float2*)(p + 24);
        ds += a.x * a.x + a.y * a.y + b.x * b.x + b.y * b.y +
              c.x * c.x + c.y * c.y + d.x * d.x + d.y * d.y;
        KH[kt] = __builtin_bit_cast(bf16x8, make_uint4(pk2(a.x, a.y), pk2(b.x, b.y),
                                                       pk2(c.x, c.y), pk2(d.x, d.y)));
      }
      ds += __shfl_xor(ds, 32);
      nrm = ds * 0.0625f;
    }
    // barrier: V(t+1) visible; K(t+2)/V(t+2) drained (issued a full phase ago)
    __syncthreads();
  }
  // ---- S1 partials (shared slab per (bh,nc); twins cover disjoint m) ----
  {
    float* o = s1p + (size_t)(bh * NC + nc) * (MM * 64);
#pragma unroll
    for (int et = 0; et < 2; ++et)
#pragma unroll
      for (int i = 0; i < 16; ++i) {
        const int m = mslice * 32 + 4 * lh + (i & 3) + 8 * (i >> 2);
        o[m * 64 + et * 32 + l31] = accS[et][i];
      }
  }
  // ---- S2 reduce via LDS scratch (reuse smc) ----
  {
    float* scr = (float*)smc;  // [256][8]
#pragma unroll
    for (int j = 0; j < 8; ++j) scr[t * 8 + j] = s2loc[j];
    __syncthreads();
    if (doS2 && t < 64) {
      float s = 0.f;
      for (int k2 = 0; k2 < 32; ++k2) s += scr[((k2 << 3) | (t >> 3)) * 8 + (t & 7)];
      s2p[(size_t)(bh * NC + nc) * 64 + t] = s;
    }
  }
  // ---- global max: per-wave reduce + atomic ----
#pragma unroll
  for (int off = 32; off; off >>= 1) gmax = fmaxf(gmax, __shfl_xor(gmax, off));
  if (l == 0) {
    unsigned b = __float_as_uint(gmax);
    unsigned key = (b & 0x80000000u) ? ~b : (b | 0x80000000u);
    atomicMax(kmaxp, key);
  }
}

// ---------------- ctx_finalize v2 (16-way per bh — 1024 blocks, 4/CU) ----------------------------
__global__ void ctx_finalize(const float* __restrict__ s1p, const float* __restrict__ s2p,
                             const unsigned* __restrict__ kmaxp, unsigned short* __restrict__ cbU,
                             float* __restrict__ epstP, int NC) {
  __shared__ float ctxl[16 * 64];
  __shared__ float s2s[64];
  __shared__ float csr[4 * 64];
  const int t = threadIdx.x;
  const int bh = blockIdx.x >> 4, gg = blockIdx.x & 15;   // gg = 16-row slice = kt index
  const unsigned key = *kmaxp;
  const unsigned b = (key & 0x80000000u) ? (key & 0x7fffffffu) : ~key;
  const float stab = __uint_as_float(b);
  const float esc = RATIO * __expf(-stab);
  if (t < 64) {
    float s = 0.f;
    for (int nc = 0; nc < NC; ++nc) s += s2p[(size_t)(bh * NC + nc) * 64 + t];
    s2s[t] = RATIO * EPSK * s;
  }
  __syncthreads();
  const int e = t & 63, w = t >> 6;
  float cs = 0.f;
#pragma unroll
  for (int i = 0; i < 4; ++i) {
    const int ml = i * 4 + w;                     // local m within this 16-row slice
    const int idx = (gg * 16 + ml) * 64 + e;      // global (m, e)
    float s = 0.f;
#pragma unroll
    for (int nc = 0; nc < 8; ++nc) s += s1p[(size_t)(bh * NC + nc) * 16384 + idx];
    const float val = esc * s + s2s[e];
    ctxl[ml * 64 + e] = val;
    cs += val;
  }
  csr[w * 64 + e] = cs;
  __syncthreads();
  if (t < 64)
    epstP[(size_t)(bh * 16 + gg) * 64 + t] =
        RATIO * EPSK * (csr[t] + csr[64 + t] + csr[128 + t] + csr[192 + t]);
  // pack cb B-frags for this slice: kt = gg, et = 0/1 (threads 0..127)
  if (t < 128) {
    const int et = t >> 6, l = t & 63;
    unsigned short pk[8];
#pragma unroll
    for (int j = 0; j < 8; ++j) {
      const int ml = 8 * (l >> 5) + j;
      const int e2 = et * 32 + (l & 31);
      pk[j] = bfu(ctxl[ml * 64 + e2]);
    }
    uint4 u = make_uint4(pk[0] | ((unsigned)pk[1] << 16), pk[2] | ((unsigned)pk[3] << 16),
                         pk[4] | ((unsigned)pk[5] << 16), pk[6] | ((unsigned)pk[7] << 16));
    *(uint4*)(cbU + (size_t)bh * 16384 + (size_t)((gg * 2 + et) * 64 + l) * 8) = u;
  }
}

// ---------------- q_pass v10 (r18 version restored: grid NBH*32, cb prefetch, single-bf16 Q) ------
__global__ __launch_bounds__(256, 3) void q_pass(
    const float* __restrict__ qq, const bf16x8* __restrict__ paG,
    const bf16x8* __restrict__ cbG, const float* __restrict__ epstP,
    float* __restrict__ outp) {
  const int t = threadIdx.x, l = t & 63, wv = t >> 6;
  const int l31 = l & 31, lh = l >> 5;
  const int bid = blockIdx.x, bh = bid >> 5, nc = bid & 31;
  const float* qb = qq + (size_t)bh * NN * DD;
  float* ob = outp + (size_t)bh * NN * DD;
  const int base = nc * 128 + wv * 32;
  const bf16x8* cbB = cbG + (size_t)bh * 2048;

  float ept0 = 0.f, ept1 = 0.f;
#pragma unroll
  for (int g = 0; g < 16; ++g) {
    ept0 += epstP[(size_t)(bh * 16 + g) * 64 + l31];
    ept1 += epstP[(size_t)(bh * 16 + g) * 64 + 32 + l31];
  }

  bf16x8 QH[4];
  float ds = 0.f;
#pragma unroll
  for (int kt = 0; kt < 4; ++kt) {
    const float* p = qb + (size_t)(base + l31) * DD + kt * 16 + 8 * lh;
    float x[8];
    *(float4*)&x[0] = *(const float4*)p;
    *(float4*)&x[4] = *(const float4*)(p + 4);
#pragma unroll
    for (int j = 0; j < 8; ++j) ds += x[j] * x[j];
    QH[kt] = __builtin_bit_cast(bf16x8, make_uint4(pk2(x[0], x[1]), pk2(x[2], x[3]),
                                                   pk2(x[4], x[5]), pk2(x[6], x[7])));
  }
  ds += __shfl_xor(ds, 32);
  const float diag = ds * 0.0625f;

  f32x16 out0, out1;
#pragma unroll
  for (int i = 0; i < 16; ++i) { out0[i] = 0.f; out1[i] = 0.f; }
  float lmax = -3.0e38f;

  bf16x8 pa[4], cbv[4];
#pragma unroll
  for (int kt = 0; kt < 4; ++kt) pa[kt] = paG[kt * 64 + l];
#pragma unroll
  for (int j = 0; j < 4; ++j) cbv[j] = cbB[j * 64 + l];

  for (int mt = 0; mt < 8; ++mt) {
    // phase A: 4 MFMA (single bf16 Q)
    f32x16 acc;
#pragma unroll
    for (int i = 0; i < 16; ++i) acc[i] = 0.f;
#pragma unroll
    for (int kt = 0; kt < 4; ++kt) acc = MFMA32(pa[kt], QH[kt], acc);
    // prefetch pa and cb for mt+1 (consumed a full mt-iteration later)
    bf16x8 pan[4], cbn[4];
    if (mt < 7) {
#pragma unroll
      for (int kt = 0; kt < 4; ++kt) pan[kt] = paG[((mt + 1) * 4 + kt) * 64 + l];
#pragma unroll
      for (int j = 0; j < 4; ++j) cbn[j] = cbB[((mt + 1) * 4 + j) * 64 + l];
    }
#pragma unroll
    for (int i = 0; i < 16; ++i) lmax = fmaxf(lmax, acc[i]);
#pragma unroll
    for (int kc = 0; kc < 2; ++kc) {
      float eA[4], eB[4];
#pragma unroll
      for (int c = 0; c < 4; ++c) {
        eA[c] = __expf(acc[kc * 8 + c] - diag);
        eB[c] = __expf(acc[kc * 8 + 4 + c] - diag);
      }
      unsigned p00 = pk2(eA[0], eA[1]), p01 = pk2(eA[2], eA[3]);
      unsigned p10 = pk2(eB[0], eB[1]), p11 = pk2(eB[2], eB[3]);
      unsigned o00 = __shfl_xor(p00, 32), o01 = __shfl_xor(p01, 32);
      unsigned o10 = __shfl_xor(p10, 32), o11 = __shfl_xor(p11, 32);
      uint4 W;
      W.x = lh ? o10 : p00;
      W.y = lh ? o11 : p01;
      W.z = lh ? p10 : o00;
      W.w = lh ? p11 : o01;
      bf16x8 af = __builtin_bit_cast(bf16x8, W);
      out0 = MFMA32(af, cbv[kc * 2 + 0], out0);
      out1 = MFMA32(af, cbv[kc * 2 + 1], out1);
    }
    if (mt < 7) {
#pragma unroll
      for (int kt = 0; kt < 4; ++kt) pa[kt] = pan[kt];
#pragma unroll
      for (int j = 0; j < 4; ++j) cbv[j] = cbn[j];
    }
  }
  const float rmaxp = fmaxf(lmax, __shfl_xor(lmax, 32));
#pragma unroll
  for (int i = 0; i < 16; ++i) {
    const int rr = 4 * lh + (i & 3) + 8 * (i >> 2);
    const float st = __shfl(rmaxp, rr);
    const float sc = RATIO * __expf(-st);
    const int row = base + rr;
    ob[(size_t)row * 64 + l31]      = sc * out0[i] + ept0;
    ob[(size_t)row * 64 + 32 + l31] = sc * out1[i] + ept1;
  }
}

extern "C" void kernel_launch(void* const* d_in, const int* in_sizes, int n_in,
                              void* d_out, int out_size, void* d_ws, size_t ws_size,
                              hipStream_t stream) {
  (void)in_sizes; (void)n_in; (void)out_size;
  const float* q    = (const float*)d_in[0];
  const float* k    = (const float*)d_in[1];
  const float* v    = (const float*)d_in[2];
  const float* proj = (const float*)d_in[3];
  float* out = (float*)d_out;
  char* wsb = (char*)d_ws;

  int NC = 8;
  auto need = [&](int nc) -> size_t {
    size_t off = 256 + 32768;                  // key + pa
    off += (size_t)nc * NBH * MM * 64 * 4;     // S1 partials
    off += (size_t)nc * NBH * 64 * 4;          // S2 partials
    off += (size_t)NBH * MM * 64 * 2;          // cb (bf16)
    off += (size_t)NBH * 16 * 64 * 4;          // epst partials (16-way)
    return off;
  };
  while (NC > 1 && need(NC) > ws_size) NC >>= 1;

  unsigned* kmaxp = (unsigned*)wsb;
  bf16x8* paG = (bf16x8*)(wsb + 256);
  float* s1p = (float*)(wsb + 256 + 32768);
  float* s2p = (float*)((char*)s1p + (size_t)NC * NBH * MM * 64 * 4);
  unsigned short* cbU = (unsigned short*)((char*)s2p + (size_t)NC * NBH * 64 * 4);
  float* epstP = (float*)((char*)cbU + (size_t)NBH * MM * 64 * 2);

  hipMemsetAsync(wsb, 0, 4, stream); // kmax key = 0 (== -inf under monotone map)
  hipLaunchKernelGGL(prep_proj, dim3(32), dim3(64), 0, stream, proj, (unsigned short*)paG);
  hipLaunchKernelGGL(k_pass, dim3(NBH * NC * 2), dim3(256), 0, stream, k, v, paG, s1p, s2p, kmaxp, NC);
  hipLaunchKernelGGL(ctx_finalize, dim3(NBH * 16), dim3(256), 0, stream, s1p, s2p, kmaxp, cbU, epstP, NC);
  hipLaunchKernelGGL(q_pass, dim3(NBH * 32), dim3(256), 0, stream, q, paG, (const bf16x8*)cbU, epstP, out);
}